// Round 5
// baseline (141.831 us; speedup 1.0000x reference)
//
#include <hip/hip_runtime.h>
#include <math.h>

#define NT 50      // targets per image
#define NG 64      // grid
#define NCLS 91
#define NCH 96     // 5 + 91
#define CPB 256    // cells per block, 1 thread per cell
#define CELL_BLOCKS 48   // 12288 / 256
#define TGT_BLOCKS  13   // ceil(50 waves / 4 waves-per-block)
#define BX (CELL_BLOCKS + TGT_BLOCKS)   // 61
#define NPART (BX * 16)                 // 976 partials

// anchors / STRIDE(8)
__device__ __constant__ float c_aw[9] = {1.25f, 2.0f, 4.125f, 3.75f, 7.75f, 7.375f, 14.5f, 19.5f, 46.625f};
__device__ __constant__ float c_ah[9] = {1.625f, 3.75f, 2.875f, 7.625f, 5.625f, 14.875f, 11.25f, 24.75f, 40.75f};

__device__ __forceinline__ float softplusf_fast(float x) {
    return __logf(1.0f + __expf(-fabsf(x))) + fmaxf(x, 0.0f);
}

__device__ __forceinline__ void target_match(float tw, float th, bool valid,
                                             float tx, float ty,
                                             bool& mask, int& cell, int& bn) {
    float area = tw * th;
    float best = -1.0f; int bna = 0;
    #pragma unroll
    for (int k = 0; k < 9; ++k) {
        float mw = fminf(tw, c_aw[k]);
        float mh = fminf(th, c_ah[k]);
        float inter = (mw > 0.0f && mh > 0.0f) ? mw * mh : 0.0f;
        float iou = inter / (area + c_aw[k] * c_ah[k] - inter);
        if (iou > best) { best = iou; bna = k; }
    }
    mask = valid && (bna < 3);    // ANCH_MASK = [0,1,2]
    bn = bna;                     // == bna % 3 when mask
    cell = mask ? (bna * 4096 + ((int)ty) * 64 + (int)tx) : -1;
}

__global__ __launch_bounds__(256) void yolo_scale_loss_kernel(
        const float* __restrict__ outp, const float* __restrict__ lab,
        unsigned* __restrict__ counter, float* __restrict__ partials,
        float* __restrict__ loss_out) {
    const int b    = blockIdx.y;
    const int tid  = threadIdx.x;
    const int lane = tid & 63;
    const int wv   = tid >> 6;
    __shared__ float s_red[4];
    __shared__ int   s_last;

    float contrib = 0.0f;

    if (blockIdx.x < CELL_BLOCKS) {
        // ========== cell role: obj loss, block-level target filtering ==========
        __shared__ float4 s_boxF[NT];           // full per-target boxes
        __shared__ float  s_areaF[NT];
        __shared__ float4 s_cbox[NT];           // compacted survivors
        __shared__ float  s_carea[NT];
        __shared__ float  s_wb[4][5];           // per-wave box bounds
        __shared__ int    s_count;
        __shared__ unsigned char s_matched[CPB];

        const int blk_start = blockIdx.x * CPB;
        const int idx = blk_start + tid;        // cell within image
        const size_t base = ((size_t)b * 12288 + idx) * NCH;

        // global loads first: HBM latency overlaps label precompute
        const float4 p03 = *(const float4*)(outp + base);
        const float  p4  = outp[base + 4];

        s_matched[tid] = 0;
        if (tid < NT) {
            const float* L = lab + (size_t)(b * NT + tid) * 5;
            float cls = L[0], x = L[1], y = L[2], w = L[3], h = L[4];
            float tx = x * NG, ty = y * NG, tw = w * NG, th = h * NG;
            bool valid = (cls + x + y + w + h) > 0.0f;
            if (!valid) { tx = ty = tw = th = 0.0f; }   // degenerate box
            bool mask; int cell, bn;
            target_match(tw, th, valid, tx, ty, mask, cell, bn);
            float hw = tw * 0.5f, hh = th * 0.5f;
            s_boxF[tid]  = make_float4(tx - hw, ty - hh, tx + hw, ty + hh);
            s_areaF[tid] = tw * th;
            if (cell >= blk_start && cell < blk_start + CPB)
                s_matched[cell - blk_start] = 1;        // benign races
        }

        // decode predicted box
        const int a = idx >> 12;
        const int j = (idx >> 6) & 63;
        const int i = idx & 63;
        float pxc = 1.0f / (1.0f + __expf(-p03.x)) + (float)i;
        float pyc = 1.0f / (1.0f + __expf(-p03.y)) + (float)j;
        float pw  = __expf(p03.z) * c_aw[a];
        float ph  = __expf(p03.w) * c_ah[a];
        float parea = pw * ph;
        float pl = pxc - pw * 0.5f, pt = pyc - ph * 0.5f;
        float pr = pxc + pw * 0.5f, pb = pyc + ph * 0.5f;

        // wave-wide pred-box bounds (butterfly)
        float BL = pl, BT = pt, BR = pr, BB = pb, PA = parea;
        #pragma unroll
        for (int off = 32; off > 0; off >>= 1) {
            BL = fminf(BL, __shfl_xor(BL, off, 64));
            BT = fminf(BT, __shfl_xor(BT, off, 64));
            BR = fmaxf(BR, __shfl_xor(BR, off, 64));
            BB = fmaxf(BB, __shfl_xor(BB, off, 64));
            PA = fminf(PA, __shfl_xor(PA, off, 64));
        }
        if (lane == 0) {
            s_wb[wv][0] = BL; s_wb[wv][1] = BT; s_wb[wv][2] = BR;
            s_wb[wv][3] = BB; s_wb[wv][4] = PA;
        }
        __syncthreads();

        // wave 0: conservative filter + ballot compaction of survivors
        if (wv == 0) {
            float bl = fminf(fminf(s_wb[0][0], s_wb[1][0]), fminf(s_wb[2][0], s_wb[3][0]));
            float bt = fminf(fminf(s_wb[0][1], s_wb[1][1]), fminf(s_wb[2][1], s_wb[3][1]));
            float br = fmaxf(fmaxf(s_wb[0][2], s_wb[1][2]), fmaxf(s_wb[2][2], s_wb[3][2]));
            float bb = fmaxf(fmaxf(s_wb[0][3], s_wb[1][3]), fmaxf(s_wb[2][3], s_wb[3][3]));
            float pa = fminf(fminf(s_wb[0][4], s_wb[1][4]), fminf(s_wb[2][4], s_wb[3][4]));
            bool keep = false;
            float4 tb = make_float4(0, 0, 0, 0); float ar = 0.0f;
            if (lane < NT) {
                tb = s_boxF[lane]; ar = s_areaF[lane];
                float iw = fminf(br, tb.z) - fmaxf(bl, tb.x);
                float ih = fminf(bb, tb.w) - fmaxf(bt, tb.y);
                float ai_ub = fmaxf(iw, 0.0f) * fmaxf(ih, 0.0f);
                // target can trigger ign for SOME cell only if 3*ai_ub > pa_min + ar
                keep = (3.0f * ai_ub > pa + ar);
            }
            unsigned long long m = __ballot(keep);
            if (keep) {
                int pos = __popcll(m & ((1ull << lane) - 1ull));
                s_cbox[pos]  = tb;
                s_carea[pos] = ar;
            }
            if (lane == 0) s_count = __popcll(m);
        }
        __syncthreads();

        // survivor loop (typically 0-5 iterations)
        const int cnt = s_count;
        bool ign = false;
        for (int t = 0; t < cnt; ++t) {
            float4 tb = s_cbox[t];
            float  ar = s_carea[t];
            float iw = fminf(pr, tb.z) - fmaxf(pl, tb.x);
            float ih = fminf(pb, tb.w) - fmaxf(pt, tb.y);
            float ai = iw * ih;
            // iou>0.5 ⇔ 3*ai > parea+ar (denominator > 0)
            ign = ign || ((fminf(iw, ih) > 0.0f) && (3.0f * ai > parea + ar));
        }
        bool matched = (s_matched[tid] != 0);
        contrib = matched ? (softplusf_fast(p4) - p4)
                          : (ign ? 0.0f : softplusf_fast(p4));
    } else {
        // ============ target role: one wave per (b, t) — xy/wh/cls ============
        const int t = (blockIdx.x - CELL_BLOCKS) * 4 + wv;
        if (t < NT) {                                     // wave-uniform
            bool mask_l = false; int cell_l = -1, bn_l = 0, cls_l = 0;
            float txl = 0, tyl = 0, twl = 0, thl = 0;
            if (lane < NT) {
                const float* L = lab + (size_t)(b * NT + lane) * 5;
                float cls = L[0], x = L[1], y = L[2], w = L[3], h = L[4];
                txl = x * NG; tyl = y * NG; twl = w * NG; thl = h * NG;
                bool valid = (cls + x + y + w + h) > 0.0f;
                target_match(twl, thl, valid, txl, tyl, mask_l, cell_l, bn_l);
                cls_l = (int)cls;
            }
            const int cell_t = __shfl(cell_l, t);
            unsigned long long same = __ballot(mask_l && (cell_l == cell_t));
            // first-target-wins dedup (absmax 0.0 rounds 1-4)
            bool winner = ((same >> t) & 1ull) &&
                          ((same & ((1ull << t) - 1ull)) == 0ull);
            if (winner) {                                 // wave-uniform
                const float tx = __shfl(txl, t), ty = __shfl(tyl, t);
                const float tw = __shfl(twl, t), th = __shfl(thl, t);
                const int   bn = __shfl(bn_l, t), cc = __shfl(cls_l, t);
                const size_t base = ((size_t)b * 12288 + cell_t) * NCH;

                float lsum = 0.0f;
                for (int c = lane; c < NCLS; c += 64) {   // coalesced 64 + 27
                    float pc = outp[base + 5 + c];
                    lsum += softplusf_fast(pc) - ((c == cc) ? pc : 0.0f);
                }
                if (lane == 0) {
                    float4 p03 = *(const float4*)(outp + base);
                    float tt0 = tx - floorf(tx), tt1 = ty - floorf(ty);
                    float tt2 = logf(tw / c_aw[bn] + 1e-16f);
                    float tt3 = logf(th / c_ah[bn] + 1e-16f);
                    float s2 = 2.0f - tw * th * (1.0f / (NG * NG));
                    lsum += softplusf_fast(p03.x) - p03.x * tt0;
                    lsum += softplusf_fast(p03.y) - p03.y * tt1;
                    float d2 = p03.z - tt2, d3 = p03.w - tt3;
                    lsum += 0.5f * s2 * (d2 * d2 + d3 * d3);
                }
                contrib = lsum;
            }
        }
    }

    // ---- block reduction → one partial per block ----
    float v = contrib;
    #pragma unroll
    for (int off = 32; off > 0; off >>= 1)
        v += __shfl_down(v, off, 64);
    if (lane == 0) s_red[wv] = v;
    __syncthreads();
    if (tid == 0) {
        float p = s_red[0] + s_red[1] + s_red[2] + s_red[3];
        const int gid = blockIdx.y * BX + blockIdx.x;
        __hip_atomic_store(&partials[gid], p, __ATOMIC_RELEASE,
                           __HIP_MEMORY_SCOPE_AGENT);
        unsigned old = __hip_atomic_fetch_add(counter, 1u, __ATOMIC_ACQ_REL,
                                              __HIP_MEMORY_SCOPE_AGENT);
        s_last = (old == NPART - 1) ? 1 : 0;
    }
    __syncthreads();

    // ---- last block performs the final reduction (no second kernel) ----
    if (s_last) {
        float v2 = 0.0f;
        for (int k = tid; k < NPART; k += 256)
            v2 += __hip_atomic_load(&partials[k], __ATOMIC_ACQUIRE,
                                    __HIP_MEMORY_SCOPE_AGENT);
        #pragma unroll
        for (int off = 32; off > 0; off >>= 1)
            v2 += __shfl_down(v2, off, 64);
        __syncthreads();                 // s_red reuse
        if (lane == 0) s_red[wv] = v2;
        __syncthreads();
        if (tid == 0)
            loss_out[0] = s_red[0] + s_red[1] + s_red[2] + s_red[3];
    }
}

extern "C" void kernel_launch(void* const* d_in, const int* in_sizes, int n_in,
                              void* d_out, int out_size, void* d_ws, size_t ws_size,
                              hipStream_t stream) {
    const float* outp = (const float*)d_in[0];
    const float* lab  = (const float*)d_in[1];
    unsigned* counter = (unsigned*)d_ws;
    float* partials   = (float*)((char*)d_ws + 256);
    float* res        = (float*)d_out;

    const int B = in_sizes[1] / (NT * 5);   // 16

    hipMemsetAsync(counter, 0, sizeof(unsigned), stream);
    dim3 grid(BX, B);                        // (61, 16)
    yolo_scale_loss_kernel<<<grid, 256, 0, stream>>>(outp, lab, counter, partials, res);
}

// Round 6
// 104.200 us; speedup vs baseline: 1.3611x; 1.3611x over previous
//
#include <hip/hip_runtime.h>
#include <math.h>

#define NT 50      // targets per image
#define NG 64      // grid
#define NCLS 91
#define NCH 96     // 5 + 91
#define CPB 256    // cells per block, 1 thread per cell
#define CELL_BLOCKS 48   // 12288 / 256
#define TGT_BLOCKS  13   // ceil(50 waves / 4 waves-per-block)
#define BX (CELL_BLOCKS + TGT_BLOCKS)   // 61
#define NPART (BX * 16)                 // 976 partials

// anchors / STRIDE(8)
__device__ __constant__ float c_aw[9] = {1.25f, 2.0f, 4.125f, 3.75f, 7.75f, 7.375f, 14.5f, 19.5f, 46.625f};
__device__ __constant__ float c_ah[9] = {1.625f, 3.75f, 2.875f, 7.625f, 5.625f, 14.875f, 11.25f, 24.75f, 40.75f};

__device__ __forceinline__ float softplusf_fast(float x) {
    return __logf(1.0f + __expf(-fabsf(x))) + fmaxf(x, 0.0f);
}

__device__ __forceinline__ void target_match(float tw, float th, bool valid,
                                             float tx, float ty,
                                             bool& mask, int& cell, int& bn) {
    float area = tw * th;
    float best = -1.0f; int bna = 0;
    #pragma unroll
    for (int k = 0; k < 9; ++k) {
        float mw = fminf(tw, c_aw[k]);
        float mh = fminf(th, c_ah[k]);
        float inter = (mw > 0.0f && mh > 0.0f) ? mw * mh : 0.0f;
        float iou = inter / (area + c_aw[k] * c_ah[k] - inter);
        if (iou > best) { best = iou; bna = k; }
    }
    mask = valid && (bna < 3);    // ANCH_MASK = [0,1,2]
    bn = bna;                     // == bna % 3 when mask
    cell = mask ? (bna * 4096 + ((int)ty) * 64 + (int)tx) : -1;
}

__global__ __launch_bounds__(256) void yolo_scale_loss_kernel(
        const float* __restrict__ outp, const float* __restrict__ lab,
        float* __restrict__ partials) {
    const int b    = blockIdx.y;
    const int tid  = threadIdx.x;
    const int lane = tid & 63;
    const int wv   = tid >> 6;
    __shared__ float s_red[4];

    float contrib = 0.0f;

    if (blockIdx.x < CELL_BLOCKS) {
        // ========== cell role: obj loss, block-level target filtering ==========
        __shared__ float4 s_boxF[NT];           // full per-target boxes
        __shared__ float  s_areaF[NT];
        __shared__ float4 s_cbox[NT];           // compacted survivors
        __shared__ float  s_carea[NT];
        __shared__ float  s_wb[4][5];           // per-wave box bounds
        __shared__ int    s_count;
        __shared__ unsigned char s_matched[CPB];

        const int blk_start = blockIdx.x * CPB;
        const int idx = blk_start + tid;        // cell within image
        const size_t base = ((size_t)b * 12288 + idx) * NCH;

        // global loads first: HBM latency overlaps label precompute
        const float4 p03 = *(const float4*)(outp + base);
        const float  p4  = outp[base + 4];

        s_matched[tid] = 0;
        if (tid < NT) {
            const float* L = lab + (size_t)(b * NT + tid) * 5;
            float cls = L[0], x = L[1], y = L[2], w = L[3], h = L[4];
            float tx = x * NG, ty = y * NG, tw = w * NG, th = h * NG;
            bool valid = (cls + x + y + w + h) > 0.0f;
            if (!valid) { tx = ty = tw = th = 0.0f; }   // degenerate box
            bool mask; int cell, bn;
            target_match(tw, th, valid, tx, ty, mask, cell, bn);
            float hw = tw * 0.5f, hh = th * 0.5f;
            s_boxF[tid]  = make_float4(tx - hw, ty - hh, tx + hw, ty + hh);
            s_areaF[tid] = tw * th;
            if (cell >= blk_start && cell < blk_start + CPB)
                s_matched[cell - blk_start] = 1;        // benign races
        }

        // decode predicted box
        const int a = idx >> 12;
        const int j = (idx >> 6) & 63;
        const int i = idx & 63;
        float pxc = 1.0f / (1.0f + __expf(-p03.x)) + (float)i;
        float pyc = 1.0f / (1.0f + __expf(-p03.y)) + (float)j;
        float pw  = __expf(p03.z) * c_aw[a];
        float ph  = __expf(p03.w) * c_ah[a];
        float parea = pw * ph;
        float pl = pxc - pw * 0.5f, pt = pyc - ph * 0.5f;
        float pr = pxc + pw * 0.5f, pb = pyc + ph * 0.5f;

        // wave-wide pred-box bounds (butterfly)
        float BL = pl, BT = pt, BR = pr, BB = pb, PA = parea;
        #pragma unroll
        for (int off = 32; off > 0; off >>= 1) {
            BL = fminf(BL, __shfl_xor(BL, off, 64));
            BT = fminf(BT, __shfl_xor(BT, off, 64));
            BR = fmaxf(BR, __shfl_xor(BR, off, 64));
            BB = fmaxf(BB, __shfl_xor(BB, off, 64));
            PA = fminf(PA, __shfl_xor(PA, off, 64));
        }
        if (lane == 0) {
            s_wb[wv][0] = BL; s_wb[wv][1] = BT; s_wb[wv][2] = BR;
            s_wb[wv][3] = BB; s_wb[wv][4] = PA;
        }
        __syncthreads();

        // wave 0: conservative filter + ballot compaction of survivors
        if (wv == 0) {
            float bl = fminf(fminf(s_wb[0][0], s_wb[1][0]), fminf(s_wb[2][0], s_wb[3][0]));
            float bt = fminf(fminf(s_wb[0][1], s_wb[1][1]), fminf(s_wb[2][1], s_wb[3][1]));
            float br = fmaxf(fmaxf(s_wb[0][2], s_wb[1][2]), fmaxf(s_wb[2][2], s_wb[3][2]));
            float bb = fmaxf(fmaxf(s_wb[0][3], s_wb[1][3]), fmaxf(s_wb[2][3], s_wb[3][3]));
            float pa = fminf(fminf(s_wb[0][4], s_wb[1][4]), fminf(s_wb[2][4], s_wb[3][4]));
            bool keep = false;
            float4 tb = make_float4(0, 0, 0, 0); float ar = 0.0f;
            if (lane < NT) {
                tb = s_boxF[lane]; ar = s_areaF[lane];
                float iw = fminf(br, tb.z) - fmaxf(bl, tb.x);
                float ih = fminf(bb, tb.w) - fmaxf(bt, tb.y);
                float ai_ub = fmaxf(iw, 0.0f) * fmaxf(ih, 0.0f);
                // target can trigger ign for SOME cell only if 3*ai_ub > pa_min + ar
                keep = (3.0f * ai_ub > pa + ar);
            }
            unsigned long long m = __ballot(keep);
            if (keep) {
                int pos = __popcll(m & ((1ull << lane) - 1ull));
                s_cbox[pos]  = tb;
                s_carea[pos] = ar;
            }
            if (lane == 0) s_count = __popcll(m);
        }
        __syncthreads();

        // survivor loop (typically 0-5 iterations)
        const int cnt = s_count;
        bool ign = false;
        for (int t = 0; t < cnt; ++t) {
            float4 tb = s_cbox[t];
            float  ar = s_carea[t];
            float iw = fminf(pr, tb.z) - fmaxf(pl, tb.x);
            float ih = fminf(pb, tb.w) - fmaxf(pt, tb.y);
            float ai = iw * ih;
            // iou>0.5 ⇔ 3*ai > parea+ar (denominator > 0)
            ign = ign || ((fminf(iw, ih) > 0.0f) && (3.0f * ai > parea + ar));
        }
        bool matched = (s_matched[tid] != 0);
        contrib = matched ? (softplusf_fast(p4) - p4)
                          : (ign ? 0.0f : softplusf_fast(p4));
    } else {
        // ============ target role: one wave per (b, t) — xy/wh/cls ============
        const int t = (blockIdx.x - CELL_BLOCKS) * 4 + wv;
        if (t < NT) {                                     // wave-uniform
            bool mask_l = false; int cell_l = -1, bn_l = 0, cls_l = 0;
            float txl = 0, tyl = 0, twl = 0, thl = 0;
            if (lane < NT) {
                const float* L = lab + (size_t)(b * NT + lane) * 5;
                float cls = L[0], x = L[1], y = L[2], w = L[3], h = L[4];
                txl = x * NG; tyl = y * NG; twl = w * NG; thl = h * NG;
                bool valid = (cls + x + y + w + h) > 0.0f;
                target_match(twl, thl, valid, txl, tyl, mask_l, cell_l, bn_l);
                cls_l = (int)cls;
            }
            const int cell_t = __shfl(cell_l, t);
            unsigned long long same = __ballot(mask_l && (cell_l == cell_t));
            // first-target-wins dedup (absmax 0.0 rounds 1-5)
            bool winner = ((same >> t) & 1ull) &&
                          ((same & ((1ull << t) - 1ull)) == 0ull);
            if (winner) {                                 // wave-uniform
                const float tx = __shfl(txl, t), ty = __shfl(tyl, t);
                const float tw = __shfl(twl, t), th = __shfl(thl, t);
                const int   bn = __shfl(bn_l, t), cc = __shfl(cls_l, t);
                const size_t base = ((size_t)b * 12288 + cell_t) * NCH;

                float lsum = 0.0f;
                for (int c = lane; c < NCLS; c += 64) {   // coalesced 64 + 27
                    float pc = outp[base + 5 + c];
                    lsum += softplusf_fast(pc) - ((c == cc) ? pc : 0.0f);
                }
                if (lane == 0) {
                    float4 p03 = *(const float4*)(outp + base);
                    float tt0 = tx - floorf(tx), tt1 = ty - floorf(ty);
                    float tt2 = logf(tw / c_aw[bn] + 1e-16f);
                    float tt3 = logf(th / c_ah[bn] + 1e-16f);
                    float s2 = 2.0f - tw * th * (1.0f / (NG * NG));
                    lsum += softplusf_fast(p03.x) - p03.x * tt0;
                    lsum += softplusf_fast(p03.y) - p03.y * tt1;
                    float d2 = p03.z - tt2, d3 = p03.w - tt3;
                    lsum += 0.5f * s2 * (d2 * d2 + d3 * d3);
                }
                contrib = lsum;
            }
        }
    }

    // ---- block reduction → one partial per block (plain store, no atomics) ----
    float v = contrib;
    #pragma unroll
    for (int off = 32; off > 0; off >>= 1)
        v += __shfl_down(v, off, 64);
    if (lane == 0) s_red[wv] = v;
    __syncthreads();
    if (tid == 0)
        partials[blockIdx.y * BX + blockIdx.x] = s_red[0] + s_red[1] + s_red[2] + s_red[3];
}

__global__ __launch_bounds__(256) void final_reduce_kernel(
        const float* __restrict__ partials, float* __restrict__ out) {
    __shared__ float s_red[4];
    const int tid = threadIdx.x, lane = tid & 63;
    float v = 0.0f;
    for (int i = tid; i < NPART; i += 256) v += partials[i];
    #pragma unroll
    for (int off = 32; off > 0; off >>= 1)
        v += __shfl_down(v, off, 64);
    if (lane == 0) s_red[tid >> 6] = v;
    __syncthreads();
    if (tid == 0) out[0] = s_red[0] + s_red[1] + s_red[2] + s_red[3];
}

extern "C" void kernel_launch(void* const* d_in, const int* in_sizes, int n_in,
                              void* d_out, int out_size, void* d_ws, size_t ws_size,
                              hipStream_t stream) {
    const float* outp = (const float*)d_in[0];
    const float* lab  = (const float*)d_in[1];
    float* partials   = (float*)d_ws;
    float* res        = (float*)d_out;

    const int B = in_sizes[1] / (NT * 5);   // 16

    dim3 grid(BX, B);                        // (61, 16)
    yolo_scale_loss_kernel<<<grid, 256, 0, stream>>>(outp, lab, partials);
    final_reduce_kernel<<<1, 256, 0, stream>>>(partials, res);
}